// Round 4
// baseline (213.081 us; speedup 1.0000x reference)
//
#include <hip/hip_runtime.h>
#include <math.h>

#define Hd 128
#define Wd 128
#define HW 16384      // 128*128
#define EPSc 1e-6f

typedef __attribute__((ext_vector_type(8))) short s8v;    // 8 bf16 (4 VGPRs)
typedef __attribute__((ext_vector_type(4))) float f4v;    // 4 fp32 acc

__device__ __forceinline__ unsigned short f2bf(float f) {
    unsigned int u = __float_as_uint(f);
    unsigned int r = (u + 0x7FFFu + ((u >> 16) & 1u)) >> 16;   // RNE
    return (unsigned short)r;
}

// ---------------------------------------------------------------------------
// K0: weight prep + cm zero.
//  w1h/w2h:  [tap9][co64][ci64] bf16   (36864 each)   for MFMA convs
//  ga_w1t:   [ci128][co64] fp32        (8192)
//  ga_w2t:   [ci64][co16] fp32         (1024)
//  cd_w1t:   [ci16][tap9][co16] fp32   (2304)
//  cm:       zeroed (32768)
__global__ void k_prep(const float* __restrict__ ga_w1, const float* __restrict__ ga_w2,
                       const float* __restrict__ cd_w1,
                       const float* __restrict__ ec_w1, const float* __restrict__ ec_w2,
                       float* __restrict__ ga_w1t, float* __restrict__ ga_w2t,
                       float* __restrict__ cd_w1t,
                       unsigned short* __restrict__ w1h, unsigned short* __restrict__ w2h,
                       float* __restrict__ cm) {
    int i = blockIdx.x * 256 + threadIdx.x;
    if (i < 36864) {                               // w1h [t][co][ci]
        int t = i >> 12, co = (i >> 6) & 63, ci = i & 63;
        w1h[i] = f2bf(ec_w1[(co * 64 + ci) * 9 + t]);
    } else if (i < 73728) {                        // w2h
        int j = i - 36864;
        int t = j >> 12, co = (j >> 6) & 63, ci = j & 63;
        w2h[j] = f2bf(ec_w2[(co * 64 + ci) * 9 + t]);
    } else if (i < 81920) {                        // ga_w1t [ci128][co64]
        int j = i - 73728;
        int co = j & 63, ci = j >> 6;
        ga_w1t[j] = ga_w1[co * 128 + ci];
    } else if (i < 82944) {                        // ga_w2t [ci64][co16]
        int j = i - 81920;
        int co = j & 15, ci = j >> 4;
        ga_w2t[j] = ga_w2[co * 64 + ci];
    } else if (i < 85248) {                        // cd_w1t [ci16][tap9][co16]
        int j = i - 82944;
        int co = j & 15, r = j >> 4, t = r % 9, ci = r / 9;
        cd_w1t[j] = cd_w1[(co * 16 + ci) * 9 + t];
    } else if (i < 118016) {                       // cm zero
        cm[i - 85248] = 0.f;
    }
}

// ---------------------------------------------------------------------------
// K_xh: x NCHW fp32 -> xh NHWC bf16 [b][y][x][64]. grid 128 x 256.
__global__ void k_xh(const float* __restrict__ x, unsigned short* __restrict__ xh) {
    int p = blockIdx.x * 256 + threadIdx.x;   // 0..32767
    int b = p >> 14, s = p & (HW - 1);
    const float* xp = x + (size_t)b * 64 * HW + s;
    alignas(16) unsigned short buf[64];
#pragma unroll
    for (int c = 0; c < 64; c++) buf[c] = f2bf(xp[c * HW]);
    uint4* dst = (uint4*)(xh + (size_t)p * 64);
    const uint4* src = (const uint4*)buf;
#pragma unroll
    for (int i = 0; i < 8; i++) dst[i] = src[i];
}

// ---------------------------------------------------------------------------
// K1: fused sobel + 5x5 weighted circular-variance + channel-mean.
// Per block: 16x16 output tile, 16 channels. mag/dir live only in LDS.
// Writes gx,gy (for ga1) and atomicAdds cons-mean into cm.
// grid (8,8,8): z = b*4 + channel-quadrant. block 256.
__global__ __launch_bounds__(256, 4)
void k_sobcons(const float* __restrict__ x,
               const float* __restrict__ wgx, const float* __restrict__ wgy,
               float* __restrict__ gx, float* __restrict__ gy,
               float* __restrict__ cm) {
    __shared__ float xt[484];        // 22x22 x-tile (3-halo)
    __shared__ float lm[400];        // 20x20 mag
    __shared__ float ld[400];        // 20x20 dir
    int tid = threadIdx.x;
    int tx = tid & 15, ty = tid >> 4;
    int x0 = blockIdx.x * 16, y0 = blockIdx.y * 16;
    int b = blockIdx.z >> 2, cb = (blockIdx.z & 3) * 16;
    float acc = 0.f;
    for (int c = 0; c < 16; c++) {
        int ch = cb + c;
        const float* xp = x + (size_t)(b * 64 + ch) * HW;
        float wx[9], wy[9];
#pragma unroll
        for (int i = 0; i < 9; i++) { wx[i] = wgx[ch * 9 + i]; wy[i] = wgy[ch * 9 + i]; }
        __syncthreads();    // previous channel's cons reads done
        for (int i = tid; i < 484; i += 256) {
            int yy = i / 22, xx = i - yy * 22;
            int gyy = y0 - 3 + yy, gxx = x0 - 3 + xx;
            xt[i] = (gyy >= 0 && gyy < Hd && gxx >= 0 && gxx < Wd) ? xp[gyy * Wd + gxx] : 0.f;
        }
        __syncthreads();
        for (int i = tid; i < 400; i += 256) {
            int yy = i / 20, xx = i - yy * 20;      // point (y0-2+yy, x0-2+xx)
            int gyy = y0 - 2 + yy, gxx = x0 - 2 + xx;
            float m = 0.f, d = 0.f, sx = 0.f, sy = 0.f;
            if (gyy >= 0 && gyy < Hd && gxx >= 0 && gxx < Wd) {
#pragma unroll
                for (int dy = 0; dy < 3; dy++)
#pragma unroll
                    for (int dx = 0; dx < 3; dx++) {
                        float v = xt[(yy + dy) * 22 + xx + dx];
                        sx = fmaf(wx[dy * 3 + dx], v, sx);
                        sy = fmaf(wy[dy * 3 + dx], v, sy);
                    }
                m = sqrtf(sx * sx + sy * sy + EPSc);
                d = atan2f(sy, sx);
            }
            lm[i] = m;
            ld[i] = d;
            if (yy >= 2 && yy < 18 && xx >= 2 && xx < 18) {
                int o = (b * 64 + ch) * HW + gyy * Wd + gxx;
                gx[o] = sx;
                gy[o] = sy;
            }
        }
        __syncthreads();
        float mv[25], dv[25];
        float sm = 0.f, sdm = 0.f;
#pragma unroll
        for (int r = 0; r < 5; r++)
#pragma unroll
            for (int cx = 0; cx < 5; cx++) {
                int idx = (ty + r) * 20 + tx + cx;
                float m = lm[idx], d = ld[idx];
                mv[r * 5 + cx] = m;
                dv[r * 5 + cx] = d;
                sm += m;
                sdm = fmaf(d, m, sdm);
            }
        float wmean = sdm / (sm + EPSc);
        float sv = 0.f;
#pragma unroll
        for (int t = 0; t < 25; t++) { float dd = dv[t] - wmean; sv = fmaf(dd * dd, mv[t], sv); }
        float wstd = sqrtf(sv / (sm + EPSc));
        acc += 1.f - tanhf(wstd);
    }
    atomicAdd(&cm[b * HW + (y0 + ty) * Wd + x0 + tx], acc * (1.f / 64.f));
}

// ---------------------------------------------------------------------------
// K2: 1x1 conv [64 out][128 in] + relu.  grid (128,4), block 256.
__global__ void k_ga1(const float* __restrict__ gx, const float* __restrict__ gy,
                      const float* __restrict__ w1t, const float* __restrict__ b1,
                      float* __restrict__ ga1) {
    int p = blockIdx.x * 256 + threadIdx.x;   // 0..32767
    int cb = blockIdx.y * 16;
    int b = p >> 14;
    int s = p & (HW - 1);
    const float* gxp = gx + (size_t)b * 64 * HW + s;
    const float* gyp = gy + (size_t)b * 64 * HW + s;
    float acc[16];
#pragma unroll
    for (int co = 0; co < 16; co++) acc[co] = b1[cb + co];
    for (int ci = 0; ci < 64; ci++) {
        float v = gxp[ci * HW];
        const float* wp = w1t + ci * 64 + cb;
#pragma unroll
        for (int co = 0; co < 16; co++) acc[co] = fmaf(v, wp[co], acc[co]);
    }
    for (int ci = 0; ci < 64; ci++) {
        float v = gyp[ci * HW];
        const float* wp = w1t + (64 + ci) * 64 + cb;
#pragma unroll
        for (int co = 0; co < 16; co++) acc[co] = fmaf(v, wp[co], acc[co]);
    }
    float* op = ga1 + (size_t)b * 64 * HW + s;
#pragma unroll
    for (int co = 0; co < 16; co++) op[(cb + co) * HW] = fmaxf(acc[co], 0.f);
}

// ---------------------------------------------------------------------------
// K2b: 1x1 conv [16 out][64 in] + relu. grid 128, block 256.
__global__ void k_ga2(const float* __restrict__ ga1, const float* __restrict__ w2t,
                      const float* __restrict__ b2, float* __restrict__ ga2) {
    int p = blockIdx.x * 256 + threadIdx.x;
    int b = p >> 14;
    int s = p & (HW - 1);
    const float* ip = ga1 + (size_t)b * 64 * HW + s;
    float acc[16];
#pragma unroll
    for (int co = 0; co < 16; co++) acc[co] = b2[co];
    for (int ci = 0; ci < 64; ci++) {
        float v = ip[ci * HW];
        const float* wp = w2t + ci * 16;
#pragma unroll
        for (int co = 0; co < 16; co++) acc[co] = fmaf(v, wp[co], acc[co]);
    }
    float* op = ga2 + (size_t)b * 16 * HW + s;
#pragma unroll
    for (int co = 0; co < 16; co++) op[co * HW] = fmaxf(acc[co], 0.f);
}

// ---------------------------------------------------------------------------
// K5+K6 fused: 3x3 conv [16][16] + relu + 1x1 [1][16] + sigmoid, * cm -> ew
// grid (8,8,2), block 256.
__global__ __launch_bounds__(256, 4)
void k_cd1ew(const float* __restrict__ ga2, const float* __restrict__ w1t,
             const float* __restrict__ b1, const float* __restrict__ w2,
             const float* __restrict__ b2, const float* __restrict__ cm,
             float* __restrict__ ew) {
    __shared__ float lds[16][324];
    int tid = threadIdx.x;
    int tx = tid & 15, ty = tid >> 4;
    int x0 = blockIdx.x * 16, y0 = blockIdx.y * 16;
    int b = blockIdx.z;
    const float* ip = ga2 + (size_t)b * 16 * HW;
    float acc[16];
#pragma unroll
    for (int co = 0; co < 16; co++) acc[co] = b1[co];
#pragma unroll
    for (int ci = 0; ci < 16; ci++) {
        const float* sp = ip + ci * HW;
        for (int i = tid; i < 324; i += 256) {
            int yy = i / 18, xx = i - yy * 18;
            int gy = y0 - 1 + yy, gx = x0 - 1 + xx;
            lds[ci][i] = (gy >= 0 && gy < Hd && gx >= 0 && gx < Wd) ? sp[gy * Wd + gx] : 0.f;
        }
    }
    __syncthreads();
    for (int ci = 0; ci < 16; ci++) {
        const float* wp = w1t + ci * 9 * 16;
        float pv[9];
#pragma unroll
        for (int r = 0; r < 3; r++)
#pragma unroll
            for (int cx = 0; cx < 3; cx++)
                pv[r * 3 + cx] = lds[ci][(ty + r) * 18 + tx + cx];
#pragma unroll
        for (int t = 0; t < 9; t++)
#pragma unroll
            for (int co = 0; co < 16; co++)
                acc[co] = fmaf(pv[t], wp[t * 16 + co], acc[co]);
    }
    float e = b2[0];
#pragma unroll
    for (int co = 0; co < 16; co++) e = fmaf(fmaxf(acc[co], 0.f), w2[co], e);
    float sig = 1.f / (1.f + expf(-e));
    int sp = (y0 + ty) * Wd + x0 + tx;
    ew[b * HW + sp] = sig * cm[b * HW + sp];
}

// ---------------------------------------------------------------------------
// K7/K8: 3x3 conv [64][64] via bf16 MFMA implicit GEMM, tap-split.
// Block: 8x8 output tile, 128 threads = 2 waves, each wave 32 co.
// (2 waves/block instead of 4 halves redundant B-fragment LDS reads.)
// LDS: 10x10x64 bf16 halo tile, ci-octet XOR-swizzled vs (rowlin&7).
// FINAL=0: relu -> bf16 NHWC out. FINAL=1: out = x + alpha*ew*acc (fp32 NCHW).
template <int FINAL>
__global__ __launch_bounds__(128, 2)
void k_conv64m(const unsigned short* __restrict__ inh,
               const unsigned short* __restrict__ wh,
               const float* __restrict__ bias,
               unsigned short* __restrict__ outh,
               float* __restrict__ outf,
               const float* __restrict__ x,
               const float* __restrict__ ew,
               const float* __restrict__ alpha_p) {
    __shared__ unsigned short tile[100 * 64];   // 12.8 KB
    int tid = threadIdx.x;
    int x0 = blockIdx.x * 8, y0 = blockIdx.y * 8;
    int b = blockIdx.z;
    const size_t ibase = (size_t)b * HW * 64;

    for (int i = tid; i < 800; i += 128) {
        int py = i / 80;
        int r = i - py * 80;
        int px = r >> 3, cg = r & 7;
        int gy = y0 - 1 + py, gx = x0 - 1 + px;
        uint4 v = {0u, 0u, 0u, 0u};
        if (gy >= 0 && gy < Hd && gx >= 0 && gx < Wd)
            v = *(const uint4*)(inh + ibase + (size_t)(gy * Wd + gx) * 64 + cg * 8);
        int rowlin = py * 10 + px;
        int scg = cg ^ (rowlin & 7);
        *(uint4*)(tile + rowlin * 64 + scg * 8) = v;
    }

    int lane = tid & 63;
    int wv = tid >> 6;            // 0..1
    int l15 = lane & 15, lq = lane >> 4;
    int co_base = wv * 32;

    // preload 36 A-fragments (144 VGPRs), held for whole kernel
    s8v af[9][2][2];
#pragma unroll
    for (int t = 0; t < 9; t++)
#pragma unroll
        for (int h = 0; h < 2; h++)
#pragma unroll
            for (int g = 0; g < 2; g++)
                af[t][h][g] = *(const s8v*)(wh + ((t * 64 + co_base + g * 16 + l15) * 64 + h * 32 + lq * 8));

    f4v acc[4][2];
#pragma unroll
    for (int g = 0; g < 2; g++) {
        f4v bv = *(const f4v*)(bias + co_base + g * 16 + lq * 4);
#pragma unroll
        for (int n = 0; n < 4; n++) acc[n][g] = bv;
    }

    __syncthreads();

#pragma unroll
    for (int n = 0; n < 4; n++) {
        int px = n * 16 + l15;
        int pyy = px >> 3, pxx = px & 7;
#pragma unroll
        for (int dy = 0; dy < 3; dy++) {
#pragma unroll
            for (int dx = 0; dx < 3; dx++) {
                int rowlin = (pyy + dy) * 10 + (pxx + dx);
                int sw = rowlin & 7;
                const unsigned short* tp = tile + rowlin * 64;
                s8v b0 = *(const s8v*)(tp + (lq ^ sw) * 8);
                s8v b1 = *(const s8v*)(tp + ((4 + lq) ^ sw) * 8);
                int t = dy * 3 + dx;
                acc[n][0] = __builtin_amdgcn_mfma_f32_16x16x32_bf16(af[t][0][0], b0, acc[n][0], 0, 0, 0);
                acc[n][1] = __builtin_amdgcn_mfma_f32_16x16x32_bf16(af[t][0][1], b0, acc[n][1], 0, 0, 0);
                acc[n][0] = __builtin_amdgcn_mfma_f32_16x16x32_bf16(af[t][1][0], b1, acc[n][0], 0, 0, 0);
                acc[n][1] = __builtin_amdgcn_mfma_f32_16x16x32_bf16(af[t][1][1], b1, acc[n][1], 0, 0, 0);
            }
        }
    }

#pragma unroll
    for (int n = 0; n < 4; n++) {
        int px = n * 16 + l15;
        int gyo = y0 + (px >> 3), gxo = x0 + (px & 7);
        int sp = gyo * Wd + gxo;
        if (FINAL) {
            float ae = alpha_p[0] * ew[b * HW + sp];
#pragma unroll
            for (int g = 0; g < 2; g++)
#pragma unroll
                for (int r = 0; r < 4; r++) {
                    size_t o = (size_t)(b * 64 + co_base + g * 16 + lq * 4 + r) * HW + sp;
                    outf[o] = fmaf(ae, acc[n][g][r], x[o]);
                }
        } else {
#pragma unroll
            for (int g = 0; g < 2; g++) {
                alignas(8) unsigned short pk[4];
#pragma unroll
                for (int r = 0; r < 4; r++) pk[r] = f2bf(fmaxf(acc[n][g][r], 0.f));
                *(uint2*)(outh + ibase + (size_t)sp * 64 + co_base + g * 16 + lq * 4) = *(const uint2*)pk;
            }
        }
    }
}

// ---------------------------------------------------------------------------
extern "C" void kernel_launch(void* const* d_in, const int* in_sizes, int n_in,
                              void* d_out, int out_size, void* d_ws, size_t ws_size,
                              hipStream_t stream) {
    const float* x     = (const float*)d_in[0];
    const float* wgx   = (const float*)d_in[1];
    const float* wgy   = (const float*)d_in[2];
    const float* ga_w1 = (const float*)d_in[3];
    const float* ga_b1 = (const float*)d_in[4];
    const float* ga_w2 = (const float*)d_in[5];
    const float* ga_b2 = (const float*)d_in[6];
    const float* cd_w1 = (const float*)d_in[7];
    const float* cd_b1 = (const float*)d_in[8];
    const float* cd_w2 = (const float*)d_in[9];
    const float* cd_b2 = (const float*)d_in[10];
    const float* ec_w1 = (const float*)d_in[11];
    const float* ec_b1 = (const float*)d_in[12];
    const float* ec_w2 = (const float*)d_in[13];
    const float* ec_b2 = (const float*)d_in[14];
    const float* alpha = (const float*)d_in[15];
    float* out = (float*)d_out;
    float* ws  = (float*)d_ws;

    const size_t N = 2 * 64 * HW;   // 2,097,152 floats

    // buffer plan:
    float* gx    = ws;               // N
    float* gy    = ws + N;           // N
    float* ga1   = ws + 2 * N;       // N
    float* ga2   = ws + 3 * N;                    // 524288 floats
    float* cm    = ga2 + 2 * 16 * HW;             // 32768
    float* ew    = cm + 2 * HW;                   // 32768
    float* ga_w1t = ew + 2 * HW;                  // 8192
    float* ga_w2t = ga_w1t + 8192;                // 1024
    float* cd_w1t = ga_w2t + 1024;                // 2304
    unsigned short* w1h = (unsigned short*)(cd_w1t + 2304);  // 36864 shorts
    unsigned short* w2h = w1h + 36864;                       // 36864 shorts
    unsigned short* xh   = (unsigned short*)(ws + 4 * N);    // 2M shorts
    unsigned short* ee1h = xh + N;                           // 2M shorts

    k_prep<<<462, 256, 0, stream>>>(ga_w1, ga_w2, cd_w1, ec_w1, ec_w2,
                                    ga_w1t, ga_w2t, cd_w1t, w1h, w2h, cm);
    k_xh<<<128, 256, 0, stream>>>(x, xh);
    k_sobcons<<<dim3(8, 8, 8), 256, 0, stream>>>(x, wgx, wgy, gx, gy, cm);
    k_ga1<<<dim3(128, 4), 256, 0, stream>>>(gx, gy, ga_w1t, ga_b1, ga1);
    k_ga2<<<128, 256, 0, stream>>>(ga1, ga_w2t, ga_b2, ga2);
    k_cd1ew<<<dim3(8, 8, 2), 256, 0, stream>>>(ga2, cd_w1t, cd_b1, cd_w2, cd_b2, cm, ew);
    k_conv64m<0><<<dim3(16, 16, 2), 128, 0, stream>>>(xh, w1h, ec_b1, ee1h,
                                                      nullptr, nullptr, nullptr, nullptr);
    k_conv64m<1><<<dim3(16, 16, 2), 128, 0, stream>>>(ee1h, w2h, ec_b2, nullptr,
                                                      out, x, ew, alpha);
}

// Round 5
// 192.841 us; speedup vs baseline: 1.1050x; 1.1050x over previous
//
#include <hip/hip_runtime.h>
#include <math.h>

#define Hd 128
#define Wd 128
#define HW 16384      // 128*128
#define EPSc 1e-6f

typedef __attribute__((ext_vector_type(8))) short s8v;    // 8 bf16 (4 VGPRs)
typedef __attribute__((ext_vector_type(4))) float f4v;    // 4 fp32 acc

__device__ __forceinline__ unsigned short f2bf(float f) {
    unsigned int u = __float_as_uint(f);
    unsigned int r = (u + 0x7FFFu + ((u >> 16) & 1u)) >> 16;   // RNE
    return (unsigned short)r;
}

// ---------------------------------------------------------------------------
// K0: weight prep + cm zero.
__global__ void k_prep(const float* __restrict__ ga_w1, const float* __restrict__ ga_w2,
                       const float* __restrict__ cd_w1,
                       const float* __restrict__ ec_w1, const float* __restrict__ ec_w2,
                       float* __restrict__ ga_w1t, float* __restrict__ ga_w2t,
                       float* __restrict__ cd_w1t,
                       unsigned short* __restrict__ w1h, unsigned short* __restrict__ w2h,
                       float* __restrict__ cm) {
    int i = blockIdx.x * 256 + threadIdx.x;
    if (i < 36864) {                               // w1h [t][co][ci]
        int t = i >> 12, co = (i >> 6) & 63, ci = i & 63;
        w1h[i] = f2bf(ec_w1[(co * 64 + ci) * 9 + t]);
    } else if (i < 73728) {                        // w2h
        int j = i - 36864;
        int t = j >> 12, co = (j >> 6) & 63, ci = j & 63;
        w2h[j] = f2bf(ec_w2[(co * 64 + ci) * 9 + t]);
    } else if (i < 81920) {                        // ga_w1t [ci128][co64]
        int j = i - 73728;
        int co = j & 63, ci = j >> 6;
        ga_w1t[j] = ga_w1[co * 128 + ci];
    } else if (i < 82944) {                        // ga_w2t [ci64][co16]
        int j = i - 81920;
        int co = j & 15, ci = j >> 4;
        ga_w2t[j] = ga_w2[co * 64 + ci];
    } else if (i < 85248) {                        // cd_w1t [ci16][tap9][co16]
        int j = i - 82944;
        int co = j & 15, r = j >> 4, t = r % 9, ci = r / 9;
        cd_w1t[j] = cd_w1[(co * 16 + ci) * 9 + t];
    } else if (i < 118016) {                       // cm zero
        cm[i - 85248] = 0.f;
    }
}

// ---------------------------------------------------------------------------
// K_xh: x NCHW fp32 -> xh NHWC bf16 [b][y][x][64]. grid 128 x 256.
__global__ void k_xh(const float* __restrict__ x, unsigned short* __restrict__ xh) {
    int p = blockIdx.x * 256 + threadIdx.x;   // 0..32767
    int b = p >> 14, s = p & (HW - 1);
    const float* xp = x + (size_t)b * 64 * HW + s;
    alignas(16) unsigned short buf[64];
#pragma unroll
    for (int c = 0; c < 64; c++) buf[c] = f2bf(xp[c * HW]);
    uint4* dst = (uint4*)(xh + (size_t)p * 64);
    const uint4* src = (const uint4*)buf;
#pragma unroll
    for (int i = 0; i < 8; i++) dst[i] = src[i];
}

// ---------------------------------------------------------------------------
// K1: fused sobel + 5x5 weighted circular-variance + channel-mean.
// 16x16 tile, 4 channels per block. grid (8,8,32): z = b*16 + cq.
// 8 blocks/CU (32 waves) for latency hiding; lm/ld stride 24 (2-way banks = free).
__global__ __launch_bounds__(256, 8)
void k_sobcons(const float* __restrict__ x,
               const float* __restrict__ wgx, const float* __restrict__ wgy,
               float* __restrict__ gx, float* __restrict__ gy,
               float* __restrict__ cm) {
    __shared__ float xt[484];        // 22x22 x-tile (3-halo)
    __shared__ float lm[480];        // 20 rows x stride 24
    __shared__ float ld[480];
    int tid = threadIdx.x;
    int tx = tid & 15, ty = tid >> 4;
    int x0 = blockIdx.x * 16, y0 = blockIdx.y * 16;
    int b = blockIdx.z >> 4, cb = (blockIdx.z & 15) * 4;
    float acc = 0.f;
    for (int c = 0; c < 4; c++) {
        int ch = cb + c;
        const float* xp = x + (size_t)(b * 64 + ch) * HW;
        float wx[9], wy[9];
#pragma unroll
        for (int i = 0; i < 9; i++) { wx[i] = wgx[ch * 9 + i]; wy[i] = wgy[ch * 9 + i]; }
        __syncthreads();    // previous channel's cons reads done
        for (int i = tid; i < 484; i += 256) {
            int yy = i / 22, xx = i - yy * 22;
            int gyy = y0 - 3 + yy, gxx = x0 - 3 + xx;
            xt[i] = (gyy >= 0 && gyy < Hd && gxx >= 0 && gxx < Wd) ? xp[gyy * Wd + gxx] : 0.f;
        }
        __syncthreads();
        for (int i = tid; i < 400; i += 256) {
            int yy = i / 20, xx = i - yy * 20;      // point (y0-2+yy, x0-2+xx)
            int gyy = y0 - 2 + yy, gxx = x0 - 2 + xx;
            float m = 0.f, d = 0.f, sx = 0.f, sy = 0.f;
            if (gyy >= 0 && gyy < Hd && gxx >= 0 && gxx < Wd) {
#pragma unroll
                for (int dy = 0; dy < 3; dy++)
#pragma unroll
                    for (int dx = 0; dx < 3; dx++) {
                        float v = xt[(yy + dy) * 22 + xx + dx];
                        sx = fmaf(wx[dy * 3 + dx], v, sx);
                        sy = fmaf(wy[dy * 3 + dx], v, sy);
                    }
                m = sqrtf(sx * sx + sy * sy + EPSc);
                d = atan2f(sy, sx);
            }
            lm[yy * 24 + xx] = m;
            ld[yy * 24 + xx] = d;
            if (yy >= 2 && yy < 18 && xx >= 2 && xx < 18) {
                int o = (b * 64 + ch) * HW + gyy * Wd + gxx;
                gx[o] = sx;
                gy[o] = sy;
            }
        }
        __syncthreads();
        float mv[25], dv[25];
        float sm = 0.f, sdm = 0.f;
#pragma unroll
        for (int r = 0; r < 5; r++)
#pragma unroll
            for (int cx = 0; cx < 5; cx++) {
                int idx = (ty + r) * 24 + tx + cx;
                float m = lm[idx], d = ld[idx];
                mv[r * 5 + cx] = m;
                dv[r * 5 + cx] = d;
                sm += m;
                sdm = fmaf(d, m, sdm);
            }
        float wmean = sdm / (sm + EPSc);
        float sv = 0.f;
#pragma unroll
        for (int t = 0; t < 25; t++) { float dd = dv[t] - wmean; sv = fmaf(dd * dd, mv[t], sv); }
        float wstd = sqrtf(sv / (sm + EPSc));
        acc += 1.f - tanhf(wstd);
    }
    atomicAdd(&cm[b * HW + (y0 + ty) * Wd + x0 + tx], acc * (1.f / 64.f));
}

// ---------------------------------------------------------------------------
// K2: 1x1 conv [64 out][128 in] + relu.  grid (128,4), block 256.
__global__ void k_ga1(const float* __restrict__ gx, const float* __restrict__ gy,
                      const float* __restrict__ w1t, const float* __restrict__ b1,
                      float* __restrict__ ga1) {
    int p = blockIdx.x * 256 + threadIdx.x;   // 0..32767
    int cb = blockIdx.y * 16;
    int b = p >> 14;
    int s = p & (HW - 1);
    const float* gxp = gx + (size_t)b * 64 * HW + s;
    const float* gyp = gy + (size_t)b * 64 * HW + s;
    float acc[16];
#pragma unroll
    for (int co = 0; co < 16; co++) acc[co] = b1[cb + co];
    for (int ci = 0; ci < 64; ci++) {
        float v = gxp[ci * HW];
        const float* wp = w1t + ci * 64 + cb;
#pragma unroll
        for (int co = 0; co < 16; co++) acc[co] = fmaf(v, wp[co], acc[co]);
    }
    for (int ci = 0; ci < 64; ci++) {
        float v = gyp[ci * HW];
        const float* wp = w1t + (64 + ci) * 64 + cb;
#pragma unroll
        for (int co = 0; co < 16; co++) acc[co] = fmaf(v, wp[co], acc[co]);
    }
    float* op = ga1 + (size_t)b * 64 * HW + s;
#pragma unroll
    for (int co = 0; co < 16; co++) op[(cb + co) * HW] = fmaxf(acc[co], 0.f);
}

// ---------------------------------------------------------------------------
// K2b: 1x1 conv [16 out][64 in] + relu. grid 128, block 256.
__global__ void k_ga2(const float* __restrict__ ga1, const float* __restrict__ w2t,
                      const float* __restrict__ b2, float* __restrict__ ga2) {
    int p = blockIdx.x * 256 + threadIdx.x;
    int b = p >> 14;
    int s = p & (HW - 1);
    const float* ip = ga1 + (size_t)b * 64 * HW + s;
    float acc[16];
#pragma unroll
    for (int co = 0; co < 16; co++) acc[co] = b2[co];
    for (int ci = 0; ci < 64; ci++) {
        float v = ip[ci * HW];
        const float* wp = w2t + ci * 16;
#pragma unroll
        for (int co = 0; co < 16; co++) acc[co] = fmaf(v, wp[co], acc[co]);
    }
    float* op = ga2 + (size_t)b * 16 * HW + s;
#pragma unroll
    for (int co = 0; co < 16; co++) op[co * HW] = fmaxf(acc[co], 0.f);
}

// ---------------------------------------------------------------------------
// K5+K6 fused: 3x3 conv [16][16] + relu + 1x1 [1][16] + sigmoid, * cm -> ew
// grid (8,8,2), block 256.
__global__ __launch_bounds__(256, 4)
void k_cd1ew(const float* __restrict__ ga2, const float* __restrict__ w1t,
             const float* __restrict__ b1, const float* __restrict__ w2,
             const float* __restrict__ b2, const float* __restrict__ cm,
             float* __restrict__ ew) {
    __shared__ float lds[16][324];
    int tid = threadIdx.x;
    int tx = tid & 15, ty = tid >> 4;
    int x0 = blockIdx.x * 16, y0 = blockIdx.y * 16;
    int b = blockIdx.z;
    const float* ip = ga2 + (size_t)b * 16 * HW;
    float acc[16];
#pragma unroll
    for (int co = 0; co < 16; co++) acc[co] = b1[co];
#pragma unroll
    for (int ci = 0; ci < 16; ci++) {
        const float* sp = ip + ci * HW;
        for (int i = tid; i < 324; i += 256) {
            int yy = i / 18, xx = i - yy * 18;
            int gy = y0 - 1 + yy, gx = x0 - 1 + xx;
            lds[ci][i] = (gy >= 0 && gy < Hd && gx >= 0 && gx < Wd) ? sp[gy * Wd + gx] : 0.f;
        }
    }
    __syncthreads();
    for (int ci = 0; ci < 16; ci++) {
        const float* wp = w1t + ci * 9 * 16;
        float pv[9];
#pragma unroll
        for (int r = 0; r < 3; r++)
#pragma unroll
            for (int cx = 0; cx < 3; cx++)
                pv[r * 3 + cx] = lds[ci][(ty + r) * 18 + tx + cx];
#pragma unroll
        for (int t = 0; t < 9; t++)
#pragma unroll
            for (int co = 0; co < 16; co++)
                acc[co] = fmaf(pv[t], wp[t * 16 + co], acc[co]);
    }
    float e = b2[0];
#pragma unroll
    for (int co = 0; co < 16; co++) e = fmaf(fmaxf(acc[co], 0.f), w2[co], e);
    float sig = 1.f / (1.f + expf(-e));
    int sp = (y0 + ty) * Wd + x0 + tx;
    ew[b * HW + sp] = sig * cm[b * HW + sp];
}

// ---------------------------------------------------------------------------
// K7/K8: 3x3 conv [64][64] via bf16 MFMA implicit GEMM, tap-split.
// Round-3 config: 8x8 output tile x 64 co, 4 waves (wave w -> co 16w..16w+15).
// LDS: 10x10x64 bf16 halo tile, ci-octet XOR-swizzled vs (rowlin&7).
// FINAL=0: relu -> bf16 NHWC out. FINAL=1: out = x + alpha*ew*acc (fp32 NCHW).
template <int FINAL>
__global__ __launch_bounds__(256, 2)
void k_conv64m(const unsigned short* __restrict__ inh,
               const unsigned short* __restrict__ wh,
               const float* __restrict__ bias,
               unsigned short* __restrict__ outh,
               float* __restrict__ outf,
               const float* __restrict__ x,
               const float* __restrict__ ew,
               const float* __restrict__ alpha_p) {
    __shared__ unsigned short tile[100 * 64];   // 12.8 KB
    int tid = threadIdx.x;
    int x0 = blockIdx.x * 8, y0 = blockIdx.y * 8;
    int b = blockIdx.z;
    const size_t ibase = (size_t)b * HW * 64;

    for (int i = tid; i < 800; i += 256) {
        int py = i / 80;
        int r = i - py * 80;
        int px = r >> 3, cg = r & 7;
        int gy = y0 - 1 + py, gx = x0 - 1 + px;
        uint4 v = {0u, 0u, 0u, 0u};
        if (gy >= 0 && gy < Hd && gx >= 0 && gx < Wd)
            v = *(const uint4*)(inh + ibase + (size_t)(gy * Wd + gx) * 64 + cg * 8);
        int rowlin = py * 10 + px;
        int scg = cg ^ (rowlin & 7);
        *(uint4*)(tile + rowlin * 64 + scg * 8) = v;
    }

    int lane = tid & 63;
    int wv = tid >> 6;
    int l15 = lane & 15, lq = lane >> 4;
    int co_base = wv * 16;

    s8v af[9][2];
#pragma unroll
    for (int t = 0; t < 9; t++)
#pragma unroll
        for (int h = 0; h < 2; h++)
            af[t][h] = *(const s8v*)(wh + ((t * 64 + co_base + l15) * 64 + h * 32 + lq * 8));

    f4v bv = *(const f4v*)(bias + co_base + lq * 4);
    f4v acc[4];
#pragma unroll
    for (int n = 0; n < 4; n++) acc[n] = bv;

    __syncthreads();

#pragma unroll
    for (int n = 0; n < 4; n++) {
        int px = n * 16 + l15;
        int pyy = px >> 3, pxx = px & 7;
#pragma unroll
        for (int dy = 0; dy < 3; dy++) {
#pragma unroll
            for (int dx = 0; dx < 3; dx++) {
                int rowlin = (pyy + dy) * 10 + (pxx + dx);
                int sw = rowlin & 7;
                const unsigned short* tp = tile + rowlin * 64;
                s8v b0 = *(const s8v*)(tp + (lq ^ sw) * 8);
                s8v b1 = *(const s8v*)(tp + ((4 + lq) ^ sw) * 8);
                int t = dy * 3 + dx;
                acc[n] = __builtin_amdgcn_mfma_f32_16x16x32_bf16(af[t][0], b0, acc[n], 0, 0, 0);
                acc[n] = __builtin_amdgcn_mfma_f32_16x16x32_bf16(af[t][1], b1, acc[n], 0, 0, 0);
            }
        }
    }

#pragma unroll
    for (int n = 0; n < 4; n++) {
        int px = n * 16 + l15;
        int gyo = y0 + (px >> 3), gxo = x0 + (px & 7);
        int sp = gyo * Wd + gxo;
        if (FINAL) {
            float ae = alpha_p[0] * ew[b * HW + sp];
#pragma unroll
            for (int r = 0; r < 4; r++) {
                size_t o = (size_t)(b * 64 + co_base + lq * 4 + r) * HW + sp;
                outf[o] = fmaf(ae, acc[n][r], x[o]);
            }
        } else {
            alignas(8) unsigned short pk[4];
#pragma unroll
            for (int r = 0; r < 4; r++) pk[r] = f2bf(fmaxf(acc[n][r], 0.f));
            *(uint2*)(outh + ibase + (size_t)sp * 64 + co_base + lq * 4) = *(const uint2*)pk;
        }
    }
}

// ---------------------------------------------------------------------------
extern "C" void kernel_launch(void* const* d_in, const int* in_sizes, int n_in,
                              void* d_out, int out_size, void* d_ws, size_t ws_size,
                              hipStream_t stream) {
    const float* x     = (const float*)d_in[0];
    const float* wgx   = (const float*)d_in[1];
    const float* wgy   = (const float*)d_in[2];
    const float* ga_w1 = (const float*)d_in[3];
    const float* ga_b1 = (const float*)d_in[4];
    const float* ga_w2 = (const float*)d_in[5];
    const float* ga_b2 = (const float*)d_in[6];
    const float* cd_w1 = (const float*)d_in[7];
    const float* cd_b1 = (const float*)d_in[8];
    const float* cd_w2 = (const float*)d_in[9];
    const float* cd_b2 = (const float*)d_in[10];
    const float* ec_w1 = (const float*)d_in[11];
    const float* ec_b1 = (const float*)d_in[12];
    const float* ec_w2 = (const float*)d_in[13];
    const float* ec_b2 = (const float*)d_in[14];
    const float* alpha = (const float*)d_in[15];
    float* out = (float*)d_out;
    float* ws  = (float*)d_ws;

    const size_t N = 2 * 64 * HW;   // 2,097,152 floats

    // buffer plan:
    float* gx    = ws;               // N
    float* gy    = ws + N;           // N
    float* ga1   = ws + 2 * N;       // N
    float* ga2   = ws + 3 * N;                    // 524288 floats
    float* cm    = ga2 + 2 * 16 * HW;             // 32768
    float* ew    = cm + 2 * HW;                   // 32768
    float* ga_w1t = ew + 2 * HW;                  // 8192
    float* ga_w2t = ga_w1t + 8192;                // 1024
    float* cd_w1t = ga_w2t + 1024;                // 2304
    unsigned short* w1h = (unsigned short*)(cd_w1t + 2304);  // 36864 shorts
    unsigned short* w2h = w1h + 36864;                       // 36864 shorts
    unsigned short* xh   = (unsigned short*)(ws + 4 * N);    // 2M shorts
    unsigned short* ee1h = xh + N;                           // 2M shorts

    k_prep<<<462, 256, 0, stream>>>(ga_w1, ga_w2, cd_w1, ec_w1, ec_w2,
                                    ga_w1t, ga_w2t, cd_w1t, w1h, w2h, cm);
    k_xh<<<128, 256, 0, stream>>>(x, xh);
    k_sobcons<<<dim3(8, 8, 32), 256, 0, stream>>>(x, wgx, wgy, gx, gy, cm);
    k_ga1<<<dim3(128, 4), 256, 0, stream>>>(gx, gy, ga_w1t, ga_b1, ga1);
    k_ga2<<<128, 256, 0, stream>>>(ga1, ga_w2t, ga_b2, ga2);
    k_cd1ew<<<dim3(8, 8, 2), 256, 0, stream>>>(ga2, cd_w1t, cd_b1, cd_w2, cd_b2, cm, ew);
    k_conv64m<0><<<dim3(16, 16, 2), 256, 0, stream>>>(xh, w1h, ec_b1, ee1h,
                                                      nullptr, nullptr, nullptr, nullptr);
    k_conv64m<1><<<dim3(16, 16, 2), 256, 0, stream>>>(ee1h, w2h, ec_b2, nullptr,
                                                      out, x, ew, alpha);
}